// Round 12
// baseline (40.642 us; speedup 1.0000x reference)
//
#include <hip/hip_runtime.h>
#include <hip/hip_bf16.h>
#include <math.h>

#define BB 32
#define SS 256
#define DD 128
#define KK 16
#define VV 50000
#define SK (SS*KK)     // 4096
#define LOG2E 1.44269504f
#define LN2   0.69314718f

typedef __attribute__((ext_vector_type(8))) short bf16x8;
typedef __attribute__((ext_vector_type(4))) float f32x4;
typedef __attribute__((ext_vector_type(16))) float f32x16;

static __device__ __forceinline__ short f2bf(float f) {
    __hip_bfloat16 h = __float2bfloat16(f);
    return *(short*)&h;
}

static __device__ __forceinline__ float fast_exp2(float x) {
    float r; asm("v_exp_f32 %0, %1" : "=v"(r) : "v"(x)); return r;
}
static __device__ __forceinline__ float fast_log2(float x) {
    float r; asm("v_log_f32 %0, %1" : "=v"(r) : "v"(x)); return r;
}

// byte offset of (row, d) in the [128][128] bf16 LDS tile, XOR-swizzled:
// 16B-chunk q -> q ^ (row & 15). Measured conflict-free (R10/R11: SQ_LDS_BANK_CONFLICT=0).
static __device__ __forceinline__ int lds_off(int row, int d) {
    return row * 256 + ((d * 2) ^ ((row & 15) << 4));
}

// grid (32 n-tiles, 2 m-halves, 32 batches) = 2048 blocks, 4 waves each.
// Per block: 128 cand rows gathered fp32->regs (issued first, hidden under
// A-staging), 128 latent rows fp32->bf16*log2e->LDS (32 KB), one barrier,
// MFMA acc[2][2], in-register LSE (base-2), trans-LDS, coalesced stores.
// launch_bounds(256,3): cap 168 VGPR (no spills) -> >=12 waves/CU.
__global__ __launch_bounds__(256, 3)
void neg_loss_main(const float* __restrict__ latent,   // [B,S,D] fp32
                   const int*   __restrict__ labels,   // [B,S]
                   const int*   __restrict__ samples,  // [B,S*(K-1)]
                   const float* __restrict__ embed,    // [V,D] fp32
                   float* __restrict__ out)            // [B,S,S]
{
    __shared__ char  ldsA[128 * 256];   // 32 KB: this m-half's latent rows
    __shared__ float trans[128][9];     // 4.6 KB: output transpose staging

    const int nt   = blockIdx.x;        // 0..31 candidate tile
    const int mh   = blockIdx.y;        // 0..1  latent half
    const int b    = blockIdx.z;
    const int n0   = nt * 128;
    const int m0   = mh * 128;
    const int tid  = threadIdx.x;
    const int wave = tid >> 6;
    const int lane = tid & 63;
    const int l31  = lane & 31;
    const int hi   = lane >> 5;

    // ---- candidate index for this lane's B row ----
    const int rB  = wave * 32 + l31;
    const int gc  = n0 + rB;
    const int j   = gc >> 4;
    const int k   = gc & 15;
    const int idx = (k < 15)
        ? samples[(size_t)b * (SS * (KK - 1)) + j * (KK - 1) + k]
        : labels[b * SS + j];

    // ---- issue B gather FIRST (deepest latency, hidden under A-staging) ----
    f32x4 fb[16];
    {
        const float* rowp = embed + (size_t)idx * DD + hi * 8;
        #pragma unroll
        for (int ks = 0; ks < 8; ++ks) {
            fb[2 * ks]     = *(const f32x4*)(rowp + ks * 16);
            fb[2 * ks + 1] = *(const f32x4*)(rowp + ks * 16 + 4);
        }
    }

    // ---- stage A: 128 latent rows fp32 -> bf16 * LOG2E, swizzled ds_write --
    #pragma unroll
    for (int pr = 0; pr < 2; ++pr) {
        const int r  = pr * 64 + (tid >> 2);
        const int d0 = (tid & 3) * 32;
        const float* src = latent + ((size_t)b * SS + m0 + r) * DD + d0;
        f32x4 f[8];
        #pragma unroll
        for (int c = 0; c < 8; ++c) f[c] = *(const f32x4*)(src + 4 * c);
        short o[32];
        #pragma unroll
        for (int c = 0; c < 8; ++c)
            #pragma unroll
            for (int e = 0; e < 4; ++e)
                o[4 * c + e] = f2bf(f[c][e] * LOG2E);
        #pragma unroll
        for (int c = 0; c < 4; ++c)
            *(bf16x8*)(ldsA + lds_off(r, d0 + 8 * c)) = *(bf16x8*)(o + 8 * c);
    }

    __syncthreads();   // A resident; fb long since arrived

    // ---- convert gathered half-row to MFMA A-fragments ----
    bf16x8 av[8];
    #pragma unroll
    for (int ks = 0; ks < 8; ++ks) {
        short t8[8];
        #pragma unroll
        for (int e = 0; e < 4; ++e) t8[e]     = f2bf(fb[2 * ks][e]);
        #pragma unroll
        for (int e = 0; e < 4; ++e) t8[4 + e] = f2bf(fb[2 * ks + 1][e]);
        av[ks] = *(bf16x8*)t8;
    }

    // ---- MFMA 32x32x16, swapped: D[row=cand][col=lat(scaled)] ----
    f32x16 acc[2][2] = {};
    #pragma unroll
    for (int ks = 0; ks < 8; ++ks) {
        const int d = ks * 16 + hi * 8;
        #pragma unroll
        for (int mt = 0; mt < 2; ++mt) {
            bf16x8 bv0 = *(const bf16x8*)(ldsA + lds_off(mt * 64 + l31, d));
            bf16x8 bv1 = *(const bf16x8*)(ldsA + lds_off(mt * 64 + 32 + l31, d));
            acc[mt][0] = __builtin_amdgcn_mfma_f32_32x32x16_bf16(av[ks], bv0, acc[mt][0], 0, 0, 0);
            acc[mt][1] = __builtin_amdgcn_mfma_f32_32x32x16_bf16(av[ks], bv1, acc[mt][1], 0, 0, 0);
        }
    }

    // ---- fused LSE (base-2) -> trans ----
    // D rows/lane: (reg&3)+8*(reg>>2)+4*hi; k-group0 = regs0-7, group1 = 8-15.
    const int jc = wave * 2 + hi;   // block-local j column 0..7
    #pragma unroll
    for (int mt = 0; mt < 2; ++mt) {
        #pragma unroll
        for (int f = 0; f < 2; ++f) {
            const f32x16 v = acc[mt][f];
            float pm0 = fmaxf(fmaxf(fmaxf(v[0], v[1]), fmaxf(v[2], v[3])),
                              fmaxf(fmaxf(v[4], v[5]), fmaxf(v[6], v[7])));
            float pm1 = fmaxf(fmaxf(fmaxf(v[8], v[9]), fmaxf(v[10], v[11])),
                              fmaxf(fmaxf(v[12], v[13]), fmaxf(v[14], v[15])));
            float om0 = fmaxf(pm0, __shfl_xor(pm0, 32));
            float om1 = fmaxf(pm1, __shfl_xor(pm1, 32));
            float e0 = ((fast_exp2(v[0] - om0) + fast_exp2(v[1] - om0))
                      + (fast_exp2(v[2] - om0) + fast_exp2(v[3] - om0)))
                     + ((fast_exp2(v[4] - om0) + fast_exp2(v[5] - om0))
                      + (fast_exp2(v[6] - om0) + fast_exp2(v[7] - om0)));
            float e1 = ((fast_exp2(v[8]  - om1) + fast_exp2(v[9]  - om1))
                      + (fast_exp2(v[10] - om1) + fast_exp2(v[11] - om1)))
                     + ((fast_exp2(v[12] - om1) + fast_exp2(v[13] - om1))
                      + (fast_exp2(v[14] - om1) + fast_exp2(v[15] - om1)));
            float s0 = e0 + __shfl_xor(e0, 32);
            float s1 = e1 + __shfl_xor(e1, 32);
            float pos0 = __shfl_xor(v[7], 32);  // hi=0 lanes get cand row 15
            float pos1 = v[15];                 // hi=1 lanes hold cand row 31
            const float pos = hi ? pos1 : pos0;
            const float om  = hi ? om1  : om0;
            const float s   = hi ? s1   : s0;
            const int i = mt * 64 + f * 32 + l31;   // local latent row 0..127
            trans[i][jc] = (pos - om - fast_log2(s)) * LN2;
        }
    }

    __syncthreads();   // trans complete

    // ---- store: thread i<128 writes out[b][m0+i][nt*8 .. +8) as 2x16B ----
    if (tid < 128) {
        const int i = tid;
        float r[8];
        #pragma unroll
        for (int c = 0; c < 8; ++c) r[c] = trans[i][c];
        float* dst = out + ((size_t)b * SS + m0 + i) * SS + nt * 8;
        *(f32x4*)(dst)     = *(f32x4*)(r);
        *(f32x4*)(dst + 4) = *(f32x4*)(r + 4);
    }
}

extern "C" void kernel_launch(void* const* d_in, const int* in_sizes, int n_in,
                              void* d_out, int out_size, void* d_ws, size_t ws_size,
                              hipStream_t stream) {
    const float* latent  = (const float*)d_in[0];
    const int*   labels  = (const int*)d_in[1];
    const int*   samples = (const int*)d_in[2];
    const float* embed   = (const float*)d_in[3];
    float* out = (float*)d_out;

    neg_loss_main<<<dim3(32, 2, 32), dim3(256), 0, stream>>>(
        latent, labels, samples, embed, out);
}

// Round 13
// 32.390 us; speedup vs baseline: 1.2548x; 1.2548x over previous
//
#include <hip/hip_runtime.h>
#include <hip/hip_bf16.h>
#include <math.h>

#define BB 32
#define SS 256
#define DD 128
#define KK 16
#define VV 50000
#define SK (SS*KK)     // 4096
#define LOG2E 1.44269504f
#define LN2   0.69314718f

typedef __attribute__((ext_vector_type(8))) short bf16x8;
typedef __attribute__((ext_vector_type(4))) float f32x4;
typedef __attribute__((ext_vector_type(16))) float f32x16;
typedef unsigned short ushort_t;

static __device__ __forceinline__ short f2bf(float f) {
    __hip_bfloat16 h = __float2bfloat16(f);
    return *(short*)&h;
}

static __device__ __forceinline__ float fast_exp2(float x) {
    float r; asm("v_exp_f32 %0, %1" : "=v"(r) : "v"(x)); return r;
}
static __device__ __forceinline__ float fast_log2(float x) {
    float r; asm("v_log_f32 %0, %1" : "=v"(r) : "v"(x)); return r;
}

// byte offset of (row, d) in the [256][128] bf16 LDS tile, XOR-swizzled:
// 16B-chunk q -> q ^ (row & 15). Conflict-free on frag reads (R10: 0 conflicts).
static __device__ __forceinline__ int lds_off(int row, int d) {
    return row * 256 + ((d * 2) ^ ((row & 15) << 4));
}

static __device__ __forceinline__ void gload_lds16(const void* g, void* lds) {
    __builtin_amdgcn_global_load_lds(
        (const __attribute__((address_space(1))) unsigned int*)g,
        (__attribute__((address_space(3))) unsigned int*)lds, 16, 0, 0);
}

#define NLAT (BB*SS*DD)       // 1,048,576
#define NCHUNK_LAT (NLAT/8)   // 131,072

// ---------------- K1: latent fp32 -> bf16 * LOG2E ---------------------------
__global__ __launch_bounds__(256)
void convert_lat_kernel(const float* __restrict__ latent,
                        ushort_t* __restrict__ ws_lat)
{
    int i = blockIdx.x * 256 + threadIdx.x;
    if (i >= NCHUNK_LAT) return;
    const float* src = latent + (size_t)i * 8;
    float f[8];
    *(f32x4*)(f + 0) = ((const f32x4*)src)[0];
    *(f32x4*)(f + 4) = ((const f32x4*)src)[1];
    short o[8];
    #pragma unroll
    for (int e = 0; e < 8; ++e) o[e] = f2bf(f[e] * LOG2E);
    *(bf16x8*)(ws_lat + (size_t)i * 8) = *(bf16x8*)o;
}

// ---------------- K2: persistent main (R11 structure, DMA A-stage) ----------
// grid 512 = 2 blocks/CU resident. Block: b = p>>4, two n-tiles (npair).
// Issue fb(tile0) gather -> issue 16x gload_lds (A: 256 bf16 rows, 64 KB)
// -> barrier (single vmcnt drain) -> issue fb(tile1) -> compute tile0 -> tile1.
__global__ __launch_bounds__(256, 2)
void neg_loss_persist(const ushort_t* __restrict__ lat_bf,  // [B,S,D] bf16*log2e
                      const int*   __restrict__ labels,     // [B,S]
                      const int*   __restrict__ samples,    // [B,S*(K-1)]
                      const float* __restrict__ embed,      // [V,D] fp32
                      float* __restrict__ out)              // [B,S,S]
{
    __shared__ char  ldsA[SS * 256];   // 64 KB
    __shared__ float trans[256][9];    // 9 KB

    const int p     = blockIdx.x;
    const int b     = p >> 4;
    const int npair = p & 15;
    const int tid   = threadIdx.x;
    const int wave  = tid >> 6;
    const int lane  = tid & 63;
    const int q     = lane & 15;
    const int sub   = lane >> 4;
    const int l31   = lane & 31;
    const int hi    = lane >> 5;

    // ---- candidate indices for both tiles ----
    const int rB  = wave * 32 + l31;
    const int gc0 = (npair * 2) * 128 + rB;
    const int gc1 = gc0 + 128;
    const int j0i = gc0 >> 4, k0i = gc0 & 15;
    const int j1i = gc1 >> 4, k1i = gc1 & 15;
    const int idx0 = (k0i < 15)
        ? samples[(size_t)b * (SS * (KK - 1)) + j0i * (KK - 1) + k0i]
        : labels[b * SS + j0i];
    const int idx1 = (k1i < 15)
        ? samples[(size_t)b * (SS * (KK - 1)) + j1i * (KK - 1) + k1i]
        : labels[b * SS + j1i];

    // ---- issue tile0 gather FIRST ----
    f32x4 fbA[16];
    {
        const float* rowp = embed + (size_t)idx0 * DD + hi * 8;
        #pragma unroll
        for (int ks = 0; ks < 8; ++ks) {
            fbA[2 * ks]     = *(const f32x4*)(rowp + ks * 16);
            fbA[2 * ks + 1] = *(const f32x4*)(rowp + ks * 16 + 4);
        }
    }

    // ---- A-stage via DMA: 256 bf16 rows, pre-swizzled source ----
    #pragma unroll
    for (int t = 0; t < 16; ++t) {
        const int r0 = wave * 64 + t * 4;
        const int r  = r0 + sub;
        const ushort_t* src = lat_bf + ((size_t)(b * SS + r) * DD)
                                     + ((q ^ (r & 15)) << 3);
        gload_lds16(src, ldsA + r0 * 256);
    }

    __syncthreads();   // drains vmcnt: A in LDS, fbA in regs

    // ---- issue tile1 gather now (hidden under tile0 compute) ----
    f32x4 fbB[16];
    {
        const float* rowp = embed + (size_t)idx1 * DD + hi * 8;
        #pragma unroll
        for (int ks = 0; ks < 8; ++ks) {
            fbB[2 * ks]     = *(const f32x4*)(rowp + ks * 16);
            fbB[2 * ks + 1] = *(const f32x4*)(rowp + ks * 16 + 4);
        }
    }

    // ================= two tiles =================
    #pragma unroll
    for (int t = 0; t < 2; ++t) {
        const int tile_n = npair * 2 + t;
        const int jc     = wave * 2 + hi;

        bf16x8 av[8];
        #pragma unroll
        for (int ks = 0; ks < 8; ++ks) {
            const f32x4 lo  = t ? fbB[2 * ks]     : fbA[2 * ks];
            const f32x4 hi4 = t ? fbB[2 * ks + 1] : fbA[2 * ks + 1];
            short t8[8];
            #pragma unroll
            for (int e = 0; e < 4; ++e) t8[e]     = f2bf(lo[e]);
            #pragma unroll
            for (int e = 0; e < 4; ++e) t8[4 + e] = f2bf(hi4[e]);
            av[ks] = *(bf16x8*)t8;
        }

        // ---- MFMA 32x32x16, swapped: D[row=cand][col=lat(scaled)] ----
        f32x16 acc[4][2] = {};
        #pragma unroll
        for (int ks = 0; ks < 8; ++ks) {
            const int d = ks * 16 + hi * 8;
            #pragma unroll
            for (int mt = 0; mt < 4; ++mt) {
                bf16x8 bv0 = *(const bf16x8*)(ldsA + lds_off(mt * 64 + l31, d));
                bf16x8 bv1 = *(const bf16x8*)(ldsA + lds_off(mt * 64 + 32 + l31, d));
                acc[mt][0] = __builtin_amdgcn_mfma_f32_32x32x16_bf16(av[ks], bv0, acc[mt][0], 0, 0, 0);
                acc[mt][1] = __builtin_amdgcn_mfma_f32_32x32x16_bf16(av[ks], bv1, acc[mt][1], 0, 0, 0);
            }
        }

        // ---- fused LSE (base-2) -> trans ----
        #pragma unroll
        for (int mt = 0; mt < 4; ++mt) {
            #pragma unroll
            for (int f = 0; f < 2; ++f) {
                const f32x16 v = acc[mt][f];
                float pm0 = fmaxf(fmaxf(fmaxf(v[0], v[1]), fmaxf(v[2], v[3])),
                                  fmaxf(fmaxf(v[4], v[5]), fmaxf(v[6], v[7])));
                float pm1 = fmaxf(fmaxf(fmaxf(v[8], v[9]), fmaxf(v[10], v[11])),
                                  fmaxf(fmaxf(v[12], v[13]), fmaxf(v[14], v[15])));
                float om0 = fmaxf(pm0, __shfl_xor(pm0, 32));
                float om1 = fmaxf(pm1, __shfl_xor(pm1, 32));
                float e0 = ((fast_exp2(v[0] - om0) + fast_exp2(v[1] - om0))
                          + (fast_exp2(v[2] - om0) + fast_exp2(v[3] - om0)))
                         + ((fast_exp2(v[4] - om0) + fast_exp2(v[5] - om0))
                          + (fast_exp2(v[6] - om0) + fast_exp2(v[7] - om0)));
                float e1 = ((fast_exp2(v[8]  - om1) + fast_exp2(v[9]  - om1))
                          + (fast_exp2(v[10] - om1) + fast_exp2(v[11] - om1)))
                         + ((fast_exp2(v[12] - om1) + fast_exp2(v[13] - om1))
                          + (fast_exp2(v[14] - om1) + fast_exp2(v[15] - om1)));
                float s0 = e0 + __shfl_xor(e0, 32);
                float s1 = e1 + __shfl_xor(e1, 32);
                float pos0 = __shfl_xor(v[7], 32);  // hi=0 lanes get cand row 15
                float pos1 = v[15];                 // hi=1 lanes hold cand row 31
                const float pos = hi ? pos1 : pos0;
                const float om  = hi ? om1  : om0;
                const float s   = hi ? s1   : s0;
                const int i = mt * 64 + f * 32 + l31;
                trans[i][jc] = (pos - om - fast_log2(s)) * LN2;
            }
        }

        __syncthreads();   // trans complete

        // ---- store: thread i writes out[b][i][tile_n*8 .. +8) as 2x16B ----
        {
            const int i = tid;
            float r[8];
            #pragma unroll
            for (int c = 0; c < 8; ++c) r[c] = trans[i][c];
            float* dst = out + ((size_t)b * SS + i) * SS + tile_n * 8;
            *(f32x4*)(dst)     = *(f32x4*)(r);
            *(f32x4*)(dst + 4) = *(f32x4*)(r + 4);
        }

        if (t == 0) __syncthreads();   // protect trans before tile1 overwrite
    }
}

// ---------------- fallback: R11 fused kernel (no ws needed) -----------------
__global__ __launch_bounds__(256, 2)
void neg_loss_fused(const float* __restrict__ latent,
                    const int*   __restrict__ labels,
                    const int*   __restrict__ samples,
                    const float* __restrict__ embed,
                    float* __restrict__ out)
{
    __shared__ char  ldsA[SS * 256];
    __shared__ float trans[256][9];

    const int p     = blockIdx.x;
    const int b     = p >> 4;
    const int npair = p & 15;
    const int tid   = threadIdx.x;
    const int wave  = tid >> 6;
    const int lane  = tid & 63;
    const int l31   = lane & 31;
    const int hi    = lane >> 5;

    const int rB  = wave * 32 + l31;
    const int gc0 = (npair * 2) * 128 + rB;
    const int gc1 = gc0 + 128;
    const int j0i = gc0 >> 4, k0i = gc0 & 15;
    const int j1i = gc1 >> 4, k1i = gc1 & 15;
    const int idx0 = (k0i < 15)
        ? samples[(size_t)b * (SS * (KK - 1)) + j0i * (KK - 1) + k0i]
        : labels[b * SS + j0i];
    const int idx1 = (k1i < 15)
        ? samples[(size_t)b * (SS * (KK - 1)) + j1i * (KK - 1) + k1i]
        : labels[b * SS + j1i];

    f32x4 fbA[16];
    {
        const float* rowp = embed + (size_t)idx0 * DD + hi * 8;
        #pragma unroll
        for (int ks = 0; ks < 8; ++ks) {
            fbA[2 * ks]     = *(const f32x4*)(rowp + ks * 16);
            fbA[2 * ks + 1] = *(const f32x4*)(rowp + ks * 16 + 4);
        }
    }

    #pragma unroll
    for (int pr = 0; pr < 4; ++pr) {
        const int r  = pr * 64 + (tid >> 2);
        const int d0 = (tid & 3) * 32;
        const float* src = latent + ((size_t)b * SS + r) * DD + d0;
        f32x4 f[8];
        #pragma unroll
        for (int c = 0; c < 8; ++c) f[c] = *(const f32x4*)(src + 4 * c);
        short o[32];
        #pragma unroll
        for (int c = 0; c < 8; ++c)
            #pragma unroll
            for (int e = 0; e < 4; ++e)
                o[4 * c + e] = f2bf(f[c][e] * LOG2E);
        #pragma unroll
        for (int c = 0; c < 4; ++c)
            *(bf16x8*)(ldsA + lds_off(r, d0 + 8 * c)) = *(bf16x8*)(o + 8 * c);
    }

    __syncthreads();

    f32x4 fbB[16];
    {
        const float* rowp = embed + (size_t)idx1 * DD + hi * 8;
        #pragma unroll
        for (int ks = 0; ks < 8; ++ks) {
            fbB[2 * ks]     = *(const f32x4*)(rowp + ks * 16);
            fbB[2 * ks + 1] = *(const f32x4*)(rowp + ks * 16 + 4);
        }
    }

    #pragma unroll
    for (int t = 0; t < 2; ++t) {
        const int tile_n = npair * 2 + t;
        const int jc     = wave * 2 + hi;

        bf16x8 av[8];
        #pragma unroll
        for (int ks = 0; ks < 8; ++ks) {
            const f32x4 lo  = t ? fbB[2 * ks]     : fbA[2 * ks];
            const f32x4 hi4 = t ? fbB[2 * ks + 1] : fbA[2 * ks + 1];
            short t8[8];
            #pragma unroll
            for (int e = 0; e < 4; ++e) t8[e]     = f2bf(lo[e]);
            #pragma unroll
            for (int e = 0; e < 4; ++e) t8[4 + e] = f2bf(hi4[e]);
            av[ks] = *(bf16x8*)t8;
        }

        f32x16 acc[4][2] = {};
        #pragma unroll
        for (int ks = 0; ks < 8; ++ks) {
            const int d = ks * 16 + hi * 8;
            #pragma unroll
            for (int mt = 0; mt < 4; ++mt) {
                bf16x8 bv0 = *(const bf16x8*)(ldsA + lds_off(mt * 64 + l31, d));
                bf16x8 bv1 = *(const bf16x8*)(ldsA + lds_off(mt * 64 + 32 + l31, d));
                acc[mt][0] = __builtin_amdgcn_mfma_f32_32x32x16_bf16(av[ks], bv0, acc[mt][0], 0, 0, 0);
                acc[mt][1] = __builtin_amdgcn_mfma_f32_32x32x16_bf16(av[ks], bv1, acc[mt][1], 0, 0, 0);
            }
        }

        #pragma unroll
        for (int mt = 0; mt < 4; ++mt) {
            #pragma unroll
            for (int f = 0; f < 2; ++f) {
                const f32x16 v = acc[mt][f];
                float pm0 = fmaxf(fmaxf(fmaxf(v[0], v[1]), fmaxf(v[2], v[3])),
                                  fmaxf(fmaxf(v[4], v[5]), fmaxf(v[6], v[7])));
                float pm1 = fmaxf(fmaxf(fmaxf(v[8], v[9]), fmaxf(v[10], v[11])),
                                  fmaxf(fmaxf(v[12], v[13]), fmaxf(v[14], v[15])));
                float om0 = fmaxf(pm0, __shfl_xor(pm0, 32));
                float om1 = fmaxf(pm1, __shfl_xor(pm1, 32));
                float e0 = ((fast_exp2(v[0] - om0) + fast_exp2(v[1] - om0))
                          + (fast_exp2(v[2] - om0) + fast_exp2(v[3] - om0)))
                         + ((fast_exp2(v[4] - om0) + fast_exp2(v[5] - om0))
                          + (fast_exp2(v[6] - om0) + fast_exp2(v[7] - om0)));
                float e1 = ((fast_exp2(v[8]  - om1) + fast_exp2(v[9]  - om1))
                          + (fast_exp2(v[10] - om1) + fast_exp2(v[11] - om1)))
                         + ((fast_exp2(v[12] - om1) + fast_exp2(v[13] - om1))
                          + (fast_exp2(v[14] - om1) + fast_exp2(v[15] - om1)));
                float s0 = e0 + __shfl_xor(e0, 32);
                float s1 = e1 + __shfl_xor(e1, 32);
                float pos0 = __shfl_xor(v[7], 32);
                float pos1 = v[15];
                const float pos = hi ? pos1 : pos0;
                const float om  = hi ? om1  : om0;
                const float s   = hi ? s1   : s0;
                const int i = mt * 64 + f * 32 + l31;
                trans[i][jc] = (pos - om - fast_log2(s)) * LN2;
            }
        }

        __syncthreads();

        {
            const int i = tid;
            float r[8];
            #pragma unroll
            for (int c = 0; c < 8; ++c) r[c] = trans[i][c];
            float* dst = out + ((size_t)b * SS + i) * SS + tile_n * 8;
            *(f32x4*)(dst)     = *(f32x4*)(r);
            *(f32x4*)(dst + 4) = *(f32x4*)(r + 4);
        }

        if (t == 0) __syncthreads();
    }
}

extern "C" void kernel_launch(void* const* d_in, const int* in_sizes, int n_in,
                              void* d_out, int out_size, void* d_ws, size_t ws_size,
                              hipStream_t stream) {
    const float* latent  = (const float*)d_in[0];
    const int*   labels  = (const int*)d_in[1];
    const int*   samples = (const int*)d_in[2];
    const float* embed   = (const float*)d_in[3];
    float* out = (float*)d_out;

    if (ws_size >= (size_t)NLAT * 2) {
        ushort_t* ws_lat = (ushort_t*)d_ws;
        convert_lat_kernel<<<(NCHUNK_LAT + 255) / 256, 256, 0, stream>>>(
            latent, ws_lat);
        neg_loss_persist<<<dim3(512), dim3(256), 0, stream>>>(
            ws_lat, labels, samples, embed, out);
    } else {
        neg_loss_fused<<<dim3(512), dim3(256), 0, stream>>>(
            latent, labels, samples, embed, out);
    }
}